// Round 14
// baseline (833.015 us; speedup 1.0000x reference)
//
#include <hip/hip_runtime.h>
#include <hip/hip_bf16.h>

typedef __bf16 bf16_t;
typedef __bf16 bf16x8 __attribute__((ext_vector_type(8)));
typedef float f32x4 __attribute__((ext_vector_type(4)));

#define SELU_SCALE 1.0507009873554805f
#define SELU_ALPHA 1.6732632423543772f

__device__ __forceinline__ float selu_f(float x) {
    return x > 0.0f ? SELU_SCALE * x : SELU_SCALE * SELU_ALPHA * (__expf(x) - 1.0f);
}

// load 8 elements at elem_off from p (bf16 or f32 per isf) as 8 bf16 (int4)
__device__ __forceinline__ int4 load8(const void* p, size_t elem_off, int isf) {
    if (!isf) return *(const int4*)((const bf16_t*)p + elem_off);
    const float* f = (const float*)p + elem_off;
    float4 a = ((const float4*)f)[0], b = ((const float4*)f)[1];
    union { int4 i; bf16_t h[8]; } u;
    u.h[0] = (bf16_t)a.x; u.h[1] = (bf16_t)a.y; u.h[2] = (bf16_t)a.z; u.h[3] = (bf16_t)a.w;
    u.h[4] = (bf16_t)b.x; u.h[5] = (bf16_t)b.y; u.h[6] = (bf16_t)b.z; u.h[7] = (bf16_t)b.w;
    return u.i;
}

// ---------------- dtype detect: bf16 vs f32 device buffers ----------------
__global__ void detect_dtype(const unsigned short* p, int* flag) {
    if (threadIdx.x == 0) {
        float m = 0.0f;
        for (int i = 0; i < 128; i++) {
            unsigned int u = ((unsigned int)p[i]) << 16;
            float v = __uint_as_float(u);
            v = fabsf(v);
            if (!(v <= 1e3f)) { m = 1e30f; break; }
            m = fmaxf(m, v);
        }
        *flag = (m > 1e3f) ? 1 : 0;  // 1 = inputs are float32
    }
}

// ---------------- batched vector convert ----------------
struct VDesc { const void* s; bf16_t* d; int eoff; int n; };
struct VArgs { VDesc v[19]; };
__global__ void convert_vecs(VArgs a, const int* __restrict__ flag) {
    int isf = *flag;
    VDesc vd = a.v[blockIdx.y];
    int i = blockIdx.x * 256 + threadIdx.x;
    if (i < vd.n) {
        size_t idx = (size_t)vd.eoff + i;
        vd.d[i] = isf ? (bf16_t)(((const float*)vd.s)[idx]) : ((const bf16_t*)vd.s)[idx];
    }
}

// ---------------- batched weight transpose ----------------
struct TDesc { const void* s; bf16_t* d; int eoff; int Ksrc; int Ktot; int koff; };
struct TArgs { TDesc t[31]; };
__global__ void transpose_all(TArgs a, const int* __restrict__ flag) {
    int isf = *flag;
    TDesc td = a.t[blockIdx.y];
    int i = blockIdx.x * 256 + threadIdx.x;
    if (i < 128 * td.Ksrc) {
        int n = i / td.Ksrc;
        int k = i - n * td.Ksrc;
        size_t si = (size_t)td.eoff + (size_t)k * 128 + n;
        bf16_t v = isf ? (bf16_t)(((const float*)td.s)[si]) : ((const bf16_t*)td.s)[si];
        td.d[(size_t)n * td.Ktot + td.koff + k] = v;
    }
}

// ---------------- composite edge weight: W01t = W1t @ W0t, b1p = b1 + b0@W1 --------
// W01t[n][k] = sum_m W1t[n][m] * W0t[m][k]   (both inputs pre-transposed)
__global__ void fuse_w01(const bf16_t* __restrict__ W0t, const bf16_t* __restrict__ W1t,
                         const bf16_t* __restrict__ b0, const bf16_t* __restrict__ b1,
                         bf16_t* __restrict__ W01t, bf16_t* __restrict__ b1p) {
    int idx = blockIdx.x * 256 + threadIdx.x;    // 64 blocks x 256 = 16384
    int n = idx >> 7, k = idx & 127;
    float acc = 0.f;
    for (int m = 0; m < 128; m++)
        acc += (float)W1t[n * 128 + m] * (float)W0t[m * 128 + k];
    W01t[(size_t)n * 128 + k] = (bf16_t)acc;
    if (k == 0) {
        float bb = (float)b1[n];
        for (int m = 0; m < 128; m++)
            bb += (float)b0[m] * (float)W1t[n * 128 + m];
        b1p[n] = (bf16_t)bb;
    }
}

// ---------------- CSR build (scan-free, both graphs per launch via gridDim.y) --------
__global__ void count_dst2(const int* __restrict__ d0, int* __restrict__ c0, int E0,
                           const int* __restrict__ d1, int* __restrict__ c1, int E1) {
    const int* dst = blockIdx.y ? d1 : d0;
    int* cnt = blockIdx.y ? c1 : c0;
    int E = blockIdx.y ? E1 : E0;
    int e = blockIdx.x * 256 + threadIdx.x;
    if (e < E) atomicAdd(&cnt[dst[e]], 1);
}

// rp[i] = cur[i] = fetch-add(total, cnt[i]); disjoint segments tiling [0,E)
__global__ void seg_alloc2(const int* __restrict__ c0, int* __restrict__ rp0, int* __restrict__ cu0, int n0,
                           const int* __restrict__ c1, int* __restrict__ rp1, int* __restrict__ cu1, int n1,
                           int* __restrict__ totals) {
    const int* cnt = blockIdx.y ? c1 : c0;
    int* rp = blockIdx.y ? rp1 : rp0;
    int* cu = blockIdx.y ? cu1 : cu0;
    int n = blockIdx.y ? n1 : n0;
    int* total = totals + blockIdx.y;
    int i = blockIdx.x * 256 + threadIdx.x;
    if (i < n) { int s = atomicAdd(total, cnt[i]); rp[i] = s; cu[i] = s; }
}

__global__ void csr_scatter2(const int* __restrict__ d0, int* __restrict__ cu0, int* __restrict__ e0, int E0,
                             const int* __restrict__ d1, int* __restrict__ cu1, int* __restrict__ e1, int E1) {
    const int* dst = blockIdx.y ? d1 : d0;
    int* cur = blockIdx.y ? cu1 : cu0;
    int* eids = blockIdx.y ? e1 : e0;
    int E = blockIdx.y ? E1 : E0;
    int e = blockIdx.x * 256 + threadIdx.x;
    if (e < E) {
        unsigned s = (unsigned)atomicAdd(&cur[dst[e]], 1);
        if (s < (unsigned)E) eids[s] = e;   // bounds guard: never corrupt neighbors
    }
}

// ---------------- single linear layer (external f32-or-bf16 inputs) ----------------
// out[M][N] = concat(A0[,A1])[M][K] @ Wt^T + b1 (+ b2) (+ res)
template<int K, int N>
__global__ __launch_bounds__(256) void lin1(
    int M, const void* __restrict__ A0, const void* __restrict__ A1,
    const bf16_t* __restrict__ Wt, const bf16_t* __restrict__ b1,
    const bf16_t* __restrict__ b2, const bf16_t* __restrict__ res,
    bf16_t* __restrict__ out, const int* __restrict__ flag)
{
    constexpr int SA = K + 8;
    constexpr int NCT = N / 64;          // 16-col tiles per wave (4 waves)
    __shared__ bf16_t sA[64 * SA];
    const int isf = *flag;
    const int tid = threadIdx.x;
    const int row0 = blockIdx.x * 64;
    const int lane16 = tid & 15;
    const int rgrp = tid >> 4;

    #pragma unroll
    for (int chunk = 0; chunk < K; chunk += 128) {
        const void* sp = chunk ? A1 : A0;
        for (int r = rgrp; r < 64; r += 16) {
            int rr = row0 + r; if (rr >= M) rr = M - 1;
            int4 u = load8(sp, (size_t)rr * 128 + lane16 * 8, isf);
            *(int4*)&sA[r * SA + chunk + lane16 * 8] = u;
        }
    }
    __syncthreads();

    const int lane = tid & 63, wave = tid >> 6;
    const int l15 = lane & 15, lk = lane >> 4;
    const int colbase = wave * (N / 4);
    f32x4 acc[4][NCT];
    const f32x4 zero = {0.f, 0.f, 0.f, 0.f};
    for (int rt = 0; rt < 4; rt++)
        for (int ct = 0; ct < NCT; ct++) acc[rt][ct] = zero;

    #pragma unroll
    for (int k0 = 0; k0 < K; k0 += 32) {
        bf16x8 wv[NCT];
        #pragma unroll
        for (int ct = 0; ct < NCT; ct++)
            wv[ct] = *(const bf16x8*)(Wt + (size_t)(colbase + ct * 16 + l15) * K + k0 + lk * 8);
        #pragma unroll
        for (int rt = 0; rt < 4; rt++) {
            bf16x8 av = *(const bf16x8*)(&sA[(rt * 16 + l15) * SA + k0 + lk * 8]);
            #pragma unroll
            for (int ct = 0; ct < NCT; ct++)
                acc[rt][ct] = __builtin_amdgcn_mfma_f32_16x16x32_bf16(av, wv[ct], acc[rt][ct], 0, 0, 0);
        }
    }

    #pragma unroll
    for (int rt = 0; rt < 4; rt++)
        #pragma unroll
        for (int ct = 0; ct < NCT; ct++) {
            int col = colbase + ct * 16 + l15;
            float bc = (float)b1[col] + (b2 ? (float)b2[col] : 0.0f);
            #pragma unroll
            for (int r = 0; r < 4; r++) {
                int grow = row0 + rt * 16 + lk * 4 + r;
                if (grow < M) {
                    float x = acc[rt][ct][r] + bc;
                    if (res) x += (float)res[(size_t)grow * N + col];
                    out[(size_t)grow * N + col] = (bf16_t)x;
                }
            }
        }
}

// ---------------- fused 2-layer FNN: 8 waves / 512 threads, 64-row tile ----------
// MODE 1 (edge): plane0 = E rows; plane1 = S = Psd[g0].lo + Psd[g1].hi (orig src/dst).
//   INPROJ=1: plane0 staged CONTIGUOUSLY from raw edge input; GEMM0 computes
//   E0reg = raw@W0 (REGISTERS, no LDS round-trip, no barriers); GEMM1 uses the
//   COMPOSITE weight W01t = W0@W1 on the raw plane (b1 = fused b1'); ep2 adds
//   residual E0reg + b0 from registers. 2 barriers total (was 4).
// MODE 2 (node): plane0 = V rows; plane1 = mean of Emat rows eids[rp[d]..+deg). K=256.
// MODE 3 (unpool): plane0 = A0[g0]; rank-1 rel*w1last on layer-1 preact.
//   INPROJ=1: plane1 staged from RAW c_fine; GEMM0 keeps conditioning cC in regs;
//   ep2 adds cC + b0.
template<int MODE, int INPROJ>
__global__ __launch_bounds__(512, 8) void fnn2k(
    int M,
    const bf16_t* __restrict__ A0, const bf16_t* __restrict__ Psd,
    const int* __restrict__ g0, const int* __restrict__ g1,
    const bf16_t* __restrict__ Emat, const int* __restrict__ rp,
    const int* __restrict__ degc, const int* __restrict__ eids,
    const void* __restrict__ Araw,
    const bf16_t* __restrict__ W0t, const bf16_t* __restrict__ b0,
    const bf16_t* __restrict__ W1t, const bf16_t* __restrict__ b1,
    const bf16_t* __restrict__ W2t, const bf16_t* __restrict__ b2,
    const bf16_t* __restrict__ relb, const bf16_t* __restrict__ w1last,
    const bf16_t* __restrict__ res, bf16_t* __restrict__ out,
    const bf16_t* __restrict__ finw, const bf16_t* __restrict__ finb,
    void* __restrict__ fout, const int* __restrict__ flag)
{
    constexpr int NP = (MODE == 3 && !INPROJ) ? 1 : 2;
    constexpr int K1 = (MODE == 2) ? 256 : 128;
    constexpr int PL = 64 * 136;
    __shared__ bf16_t sA[NP * PL];
    bf16_t* sH = sA + (NP - 1) * PL;

    const int isf = *flag;
    const int tid = threadIdx.x;
    const int lane16 = tid & 15;
    const int rgrp = tid >> 4;                    // 0..31 (16-lane row groups)
    const int lane = tid & 63, wave = tid >> 6;   // 8 waves
    const int l15 = lane & 15, lk = lane >> 4;
    const int colbase = wave * 16;
    const int row0 = blockIdx.x * 64;
    const bool res_lds = (res == A0);
    const f32x4 zero = {0.f, 0.f, 0.f, 0.f};

    // ---- stage planes: each 16-lane group loads rows rgrp, rgrp+32 ----
    #pragma unroll
    for (int c = 0; c < NP; c++) {
        #pragma unroll
        for (int i = 0; i < 2; i++) {
            int r = rgrp + i * 32;
            int rr = row0 + r; if (rr >= M) rr = M - 1;
            int4 u;
            if (MODE == 1 && INPROJ && c == 0) {
                // original order: contiguous streaming read of raw edge input
                u = load8(Araw, (size_t)rr * 128 + lane16 * 8, isf);
            } else if (MODE == 1 && c == 1) {
                bf16x8 pa = *(const bf16x8*)(Psd + (size_t)g0[rr] * 256 + lane16 * 8);
                bf16x8 pb = *(const bf16x8*)(Psd + (size_t)g1[rr] * 256 + 128 + lane16 * 8);
                union { int4 i4; bf16_t h[8]; } w;
                #pragma unroll
                for (int j = 0; j < 8; j++) w.h[j] = (bf16_t)((float)pa[j] + (float)pb[j]);
                u = w.i4;
            } else if (MODE == 2 && c == 1) {
                int beg = rp[rr], deg = degc[rr];
                float a8[8] = {0.f, 0.f, 0.f, 0.f, 0.f, 0.f, 0.f, 0.f};
                for (int e = 0; e < deg; e++) {
                    int eid = eids[beg + e];
                    bf16x8 ev = *(const bf16x8*)(Emat + (size_t)eid * 128 + lane16 * 8);
                    #pragma unroll
                    for (int j = 0; j < 8; j++) a8[j] += (float)ev[j];
                }
                float inv = 1.0f / (float)(deg > 0 ? deg : 1);
                union { int4 i4; bf16_t h[8]; } w;
                #pragma unroll
                for (int j = 0; j < 8; j++) w.h[j] = (bf16_t)(a8[j] * inv);
                u = w.i4;
            } else if (MODE == 3 && c == 1) {
                // INPROJ: raw c_fine row (direct index)
                u = load8(Araw, (size_t)rr * 128 + lane16 * 8, isf);
            } else {
                const bf16_t* sp = (MODE == 3) ? A0 + (size_t)g0[rr] * 128
                                               : A0 + (size_t)rr * 128;
                u = *(const int4*)(sp + lane16 * 8);
            }
            *(int4*)&sA[c * PL + r * 136 + lane16 * 8] = u;
        }
    }
    __syncthreads();

    // ---- INPROJ front-GEMM (W0t), result kept in REGISTERS (cC), no barriers:
    //      MODE1: cC = raw@W0 (residual E0 minus bias); MODE3: cC = c_fine@W0.
    f32x4 cC[4] = {zero, zero, zero, zero};
    if constexpr (INPROJ) {
        constexpr int PX = (MODE == 1) ? 0 : 1;
        #pragma unroll
        for (int k0 = 0; k0 < 128; k0 += 32) {
            bf16x8 w0 = *(const bf16x8*)(W0t + (size_t)(colbase + l15) * 128 + k0 + lk * 8);
            #pragma unroll
            for (int rt = 0; rt < 4; rt++) {
                bf16x8 av = *(const bf16x8*)(&sA[PX * PL + (rt * 16 + l15) * 136 + k0 + lk * 8]);
                cC[rt] = __builtin_amdgcn_mfma_f32_16x16x32_bf16(av, w0, cC[rt], 0, 0, 0);
            }
        }
    }

    // ---- GEMM1: wave computes cols [colbase, colbase+16), rows 0..63 ----
    // MODE1-INPROJ: W1t is the composite W01t, still applied to the raw plane0.
    f32x4 acc[4];
    #pragma unroll
    for (int rt = 0; rt < 4; rt++) acc[rt] = zero;
    #pragma unroll
    for (int k0 = 0; k0 < K1; k0 += 32) {
        bf16x8 w0 = *(const bf16x8*)(W1t + (size_t)(colbase + l15) * K1 + k0 + lk * 8);
        #pragma unroll
        for (int rt = 0; rt < 4; rt++) {
            bf16x8 av = *(const bf16x8*)(&sA[(k0 / 128) * PL + (rt * 16 + l15) * 136 + (k0 & 127) + lk * 8]);
            acc[rt] = __builtin_amdgcn_mfma_f32_16x16x32_bf16(av, w0, acc[rt], 0, 0, 0);
        }
    }
    // MODE 1: GEMM0/GEMM1 only read plane0; ep1 updates plane1 in place at
    // thread-private addresses -> no barrier needed. MODE 2/3 overwrite a plane
    // other waves may still be reading (MODE3's GEMM0 raw plane = sH).
    if (MODE != 1) __syncthreads();

    // ---- epilogue 1: bias (+S / +rank-1) + SELU -> sH ----
    {
        int col = colbase + l15;
        float b1c = (float)b1[col];
        float wlc = (MODE == 3) ? (float)w1last[col] : 0.0f;
        #pragma unroll
        for (int rt = 0; rt < 4; rt++)
            #pragma unroll
            for (int r = 0; r < 4; r++) {
                int lrow = rt * 16 + lk * 4 + r;
                int grow = row0 + lrow;
                float x = acc[rt][r] + b1c;
                if (MODE == 1) x += (float)sH[lrow * 136 + col];   // S plane, in place
                if (MODE == 3) {
                    float rv = (grow < M) ? (float)relb[grow] : 0.0f;
                    x += rv * wlc;
                }
                x = selu_f(x);
                sH[lrow * 136 + col] = (bf16_t)x;
            }
    }
    __syncthreads();

    // ---- GEMM2 (K2 = 128 from sH) ----
    f32x4 acc2[4];
    #pragma unroll
    for (int rt = 0; rt < 4; rt++) acc2[rt] = zero;
    #pragma unroll
    for (int k0 = 0; k0 < 128; k0 += 32) {
        bf16x8 w0 = *(const bf16x8*)(W2t + (size_t)(colbase + l15) * 128 + k0 + lk * 8);
        #pragma unroll
        for (int rt = 0; rt < 4; rt++) {
            bf16x8 av = *(const bf16x8*)(&sH[(rt * 16 + l15) * 136 + k0 + lk * 8]);
            acc2[rt] = __builtin_amdgcn_mfma_f32_16x16x32_bf16(av, w0, acc2[rt], 0, 0, 0);
        }
    }
    if (finw) __syncthreads();  // about to rewrite sH with final values

    // ---- epilogue 2: bias + residual/conditioning -> out (+ stash for out-proj) ----
    {
        int col = colbase + l15;
        float b2c = (float)b2[col];
        float b0c = INPROJ ? (float)b0[col] : 0.0f;
        #pragma unroll
        for (int rt = 0; rt < 4; rt++)
            #pragma unroll
            for (int r = 0; r < 4; r++) {
                int lrow = rt * 16 + lk * 4 + r;
                int grow = row0 + lrow;
                if (grow < M) {
                    float x = acc2[rt][r] + b2c;
                    if constexpr (INPROJ) {
                        x += cC[rt][r] + b0c;      // E0 residual (MODE1) / cond (MODE3)
                    } else {
                        if (res) {
                            float rv = (res_lds && NP > 1) ? (float)sA[lrow * 136 + col]
                                                           : (float)res[(size_t)grow * 128 + col];
                            x += rv;
                        }
                    }
                    bf16_t xb = (bf16_t)x;
                    if (out) out[(size_t)grow * 128 + col] = xb;
                    if (finw) sH[lrow * 136 + col] = xb;
                }
            }
    }

    // ---- fused final projection 128 -> 4 ----
    if (finw) {
        __syncthreads();
        if (tid < 256) {
            int orow = tid >> 2, c = tid & 3;
            int grow = row0 + orow;
            if (grow < M) {
                float s = (float)finb[c];
                #pragma unroll
                for (int k = 0; k < 128; k++)
                    s += (float)sH[orow * 136 + k] * (float)finw[k * 4 + c];
                if (isf) ((float*)fout)[(size_t)grow * 4 + c] = s;
                else     ((bf16_t*)fout)[(size_t)grow * 4 + c] = (bf16_t)s;
            }
        }
    }
}

extern "C" void kernel_launch(void* const* d_in, const int* in_sizes, int n_in,
                              void* d_out, int out_size, void* d_ws, size_t ws_size,
                              hipStream_t stream) {
    const int NC = 25000, NF = 100000, EC = 100000, EF = 400000;

    const void* v_in      = d_in[0];
    const void* c_coarse  = d_in[1];
    const void* c_fine    = d_in[2];
    const void* e_coarse  = d_in[3];
    const void* e_fine    = d_in[4];
    const void* rel_dist  = d_in[5];
    const int*  ei_c      = (const int*)d_in[6];
    const int*  ei_f      = (const int*)d_in[7];
    const int*  cluster   = (const int*)d_in[8];
    const void* in_node_w = d_in[9];
    const void* in_node_b = d_in[10];
    const void* cond_w    = d_in[11];
    const void* cond_b    = d_in[12];
    const void* edge_in_w = d_in[13];
    const void* edge_in_b = d_in[14];
    const void* bn_ew1    = d_in[15];
    const void* bn_eb1    = d_in[16];
    const void* bn_ew2    = d_in[17];
    const void* bn_eb2    = d_in[18];
    const void* bn_nw1    = d_in[19];
    const void* bn_nb1    = d_in[20];
    const void* bn_nw2    = d_in[21];
    const void* bn_nb2    = d_in[22];
    const void* unp_w1    = d_in[23];
    const void* unp_b1    = d_in[24];
    const void* unp_w2    = d_in[25];
    const void* unp_b2    = d_in[26];
    const void* up_ew1    = d_in[27];
    const void* up_eb1    = d_in[28];
    const void* up_ew2    = d_in[29];
    const void* up_eb2    = d_in[30];
    const void* up_nw1    = d_in[31];
    const void* up_nb1    = d_in[32];
    const void* up_nw2    = d_in[33];
    const void* up_nb2    = d_in[34];
    const void* out_w     = d_in[35];
    const void* out_b     = d_in[36];

    const int* src_c = ei_c, * dst_c = ei_c + EC;
    const int* src_f = ei_f, * dst_f = ei_f + EF;

    // ---- workspace carve ----
    char* base = (char*)d_ws;
    size_t off = 0;
    auto carve = [&](size_t bytes) -> void* {
        void* p = base + off;
        off += (bytes + 255) & ~(size_t)255;
        return p;
    };
    int*    flag   = (int*)carve(256);
    int*    zflag  = (int*)carve(256);          // always 0: force-bf16 path for lin1
    int*    totals = (int*)carve(256);
    bf16_t* vc     = (bf16_t*)carve((size_t)NC * 128 * 2);
    bf16_t* vf     = (bf16_t*)carve((size_t)NF * 128 * 2);
    bf16_t* ef     = (bf16_t*)carve((size_t)EF * 128 * 2);   // ec aliases the front
    bf16_t* ec     = ef;
    bf16_t* Psd    = (bf16_t*)carve((size_t)NF * 256 * 2);   // [node][Ps|Pd], reused c/f
    int*    cnti_c = (int*)carve((size_t)NC * 4);
    int*    cnti_f = (int*)carve((size_t)NF * 4);
    int*    rp_c   = (int*)carve((size_t)NC * 4);
    int*    rp_f   = (int*)carve((size_t)NF * 4);
    int*    cur_c  = (int*)carve((size_t)NC * 4);
    int*    cur_f  = (int*)carve((size_t)NF * 4);

    auto cw = [&](size_t elems) -> bf16_t* { return (bf16_t*)carve(elems * 2); };
    bf16_t* Wic    = cw(128 * 256);
    bf16_t* Wein0  = cw(128 * 128);
    bf16_t* Wein1  = cw(128 * 128);
    bf16_t* Wcond1 = cw(128 * 128);
    bf16_t* Wbe1[2] = { cw(128 * 128), cw(128 * 128) };       // We^T only (K=128)
    bf16_t* Wsd_c[2] = { cw(256 * 128), cw(256 * 128) };      // [Ws^T ; Wd^T]
    bf16_t* Wbe2[2] = { cw(128 * 128), cw(128 * 128) };
    bf16_t* Wbn1[2] = { cw(128 * 256), cw(128 * 256) };
    bf16_t* Wbn2[2] = { cw(128 * 128), cw(128 * 128) };
    bf16_t* Wunp1 = cw(128 * 128);
    bf16_t* Wunp2 = cw(128 * 128);
    bf16_t* Wue1[2] = { cw(128 * 128), cw(128 * 128) };
    bf16_t* Wsd_f[2] = { cw(256 * 128), cw(256 * 128) };
    bf16_t* Wue2[2] = { cw(128 * 128), cw(128 * 128) };
    bf16_t* Wun1[2] = { cw(128 * 256), cw(128 * 256) };
    bf16_t* Wun2[2] = { cw(128 * 128), cw(128 * 128) };
    bf16_t* W01c   = cw(128 * 128);              // composite Wein0@Wbe1[0]
    bf16_t* W01f   = cw(128 * 128);              // composite Wein1@Wue1[0]
    bf16_t* b_in   = cw(128);
    bf16_t* b_cond = cw(256);
    bf16_t* b_ein  = cw(256);
    bf16_t* b_be1  = cw(256);
    bf16_t* b_be2  = cw(256);
    bf16_t* b_bn1  = cw(256);
    bf16_t* b_bn2  = cw(256);
    bf16_t* b_unp1 = cw(128);
    bf16_t* b_unp2 = cw(128);
    bf16_t* b_ue1  = cw(256);
    bf16_t* b_ue2  = cw(256);
    bf16_t* b_un1  = cw(256);
    bf16_t* b_un2  = cw(256);
    bf16_t* b_out  = cw(8);
    bf16_t* b1pc   = cw(128);                    // fused bias b_be1 + b_ein@We1 (coarse)
    bf16_t* b1pf   = cw(128);                    // fused bias (fine)
    bf16_t* w1last = cw(128);
    bf16_t* relb   = cw(NF);
    bf16_t* foutw  = cw(512);
    bf16_t* zerob  = cw(256);                    // zero bias for Psd passes
    // index arrays at the END of the carve: even a buggy OOB scatter can't corrupt weights
    int*    eids_c = (int*)carve((size_t)EC * 4);
    int*    eids_f = (int*)carve((size_t)EF * 4);

    // ---- dtype detection + zero-init ----
    detect_dtype<<<1, 64, 0, stream>>>((const unsigned short*)in_node_b, flag);
    hipMemsetAsync(zflag, 0, 256, stream);
    hipMemsetAsync(zerob, 0, 512, stream);

    // ---- vector converts ----
    VArgs va; int vi = 0;
    auto addV = [&](const void* s, bf16_t* d, int eoff, int n) {
        va.v[vi].s = s; va.v[vi].d = d; va.v[vi].eoff = eoff; va.v[vi].n = n; vi++;
    };
    addV(in_node_b, b_in, 0, 128);
    addV(cond_b, b_cond, 0, 256);
    addV(edge_in_b, b_ein, 0, 256);
    addV(bn_eb1, b_be1, 0, 256);  addV(bn_eb2, b_be2, 0, 256);
    addV(bn_nb1, b_bn1, 0, 256);  addV(bn_nb2, b_bn2, 0, 256);
    addV(unp_b1, b_unp1, 0, 128); addV(unp_b2, b_unp2, 0, 128);
    addV(up_eb1, b_ue1, 0, 256);  addV(up_eb2, b_ue2, 0, 256);
    addV(up_nb1, b_un1, 0, 256);  addV(up_nb2, b_un2, 0, 256);
    addV(out_b, b_out, 0, 4);
    addV(unp_w1, w1last, 128 * 128, 128);
    addV(rel_dist, relb, 0, NF);
    addV(out_w, foutw, 0, 512);
    dim3 vg((NF + 255) / 256, vi);
    convert_vecs<<<vg, 256, 0, stream>>>(va, flag);

    // ---- weight transposes ----
    TArgs ta; int ti = 0;
    auto addT = [&](const void* s, bf16_t* d, int eoff, int Ksrc, int Ktot, int koff) {
        ta.t[ti].s = s; ta.t[ti].d = d; ta.t[ti].eoff = eoff;
        ta.t[ti].Ksrc = Ksrc; ta.t[ti].Ktot = Ktot; ta.t[ti].koff = koff; ti++;
    };
    addT(in_node_w, Wic, 0, 128, 256, 0);
    addT(cond_w,    Wic, 0, 128, 256, 128);
    addT(edge_in_w, Wein0, 0, 128, 128, 0);
    addT(edge_in_w, Wein1, 16384, 128, 128, 0);
    addT(cond_w,    Wcond1, 16384, 128, 128, 0);
    for (int i = 0; i < 2; i++) {
        // edge W1 split: rows [0,128)=We, [128,256)=Ws, [256,384)=Wd
        addT(bn_ew1, Wbe1[i],           i * 49152,         128, 128, 0);
        addT(bn_ew1, Wsd_c[i],          i * 49152 + 16384, 128, 128, 0);
        addT(bn_ew1, Wsd_c[i] + 16384,  i * 49152 + 32768, 128, 128, 0);
        addT(bn_ew2, Wbe2[i], i * 16384, 128, 128, 0);
        addT(bn_nw1, Wbn1[i], i * 32768, 256, 256, 0);
        addT(bn_nw2, Wbn2[i], i * 16384, 128, 128, 0);
        addT(up_ew1, Wue1[i],           i * 49152,         128, 128, 0);
        addT(up_ew1, Wsd_f[i],          i * 49152 + 16384, 128, 128, 0);
        addT(up_ew1, Wsd_f[i] + 16384,  i * 49152 + 32768, 128, 128, 0);
        addT(up_ew2, Wue2[i], i * 16384, 128, 128, 0);
        addT(up_nw1, Wun1[i], i * 32768, 256, 256, 0);
        addT(up_nw2, Wun2[i], i * 16384, 128, 128, 0);
    }
    addT(unp_w1, Wunp1, 0, 128, 128, 0);
    addT(unp_w2, Wunp2, 0, 128, 128, 0);
    dim3 tg((128 * 256 + 255) / 256, ti);
    transpose_all<<<tg, 256, 0, stream>>>(ta, flag);

    // ---- composite layer-0 edge weights (after transposes) ----
    fuse_w01<<<64, 256, 0, stream>>>(Wein0, Wbe1[0], b_ein, b_be1, W01c, b1pc);
    fuse_w01<<<64, 256, 0, stream>>>(Wein1, Wue1[0], b_ein + 128, b_ue1, W01f, b1pf);

    // ---- CSR build (counts -> scan-free segment alloc -> scatter) ----
    hipMemsetAsync(cnti_c, 0, (size_t)NC * 4, stream);
    hipMemsetAsync(cnti_f, 0, (size_t)NF * 4, stream);
    hipMemsetAsync(totals, 0, 256, stream);
    dim3 ge((EF + 255) / 256, 2), gn((NF + 255) / 256, 2);
    count_dst2<<<ge, 256, 0, stream>>>(dst_c, cnti_c, EC, dst_f, cnti_f, EF);
    seg_alloc2<<<gn, 256, 0, stream>>>(cnti_c, rp_c, cur_c, NC, cnti_f, rp_f, cur_f, NF, totals);
    csr_scatter2<<<ge, 256, 0, stream>>>(dst_c, cur_c, eids_c, EC, dst_f, cur_f, eids_f, EF);

    // ---- input projection + coarse conditioning (fused K=256) ----
    lin1<256, 128><<<(NC + 63) / 64, 256, 0, stream>>>(NC, v_in, c_coarse, Wic,
                                                       b_in, b_cond, nullptr, vc, flag);

    // ---- bottleneck (coarse) interaction layers ----
    // layer 0 edge: fused input projection (composite W01, reg residual)
    lin1<128, 256><<<(NC + 63) / 64, 256, 0, stream>>>(NC, vc, nullptr, Wsd_c[0],
                                                       zerob, nullptr, nullptr, Psd, zflag);
    fnn2k<1, 1><<<(EC + 63) / 64, 512, 0, stream>>>(
        EC, nullptr, Psd, src_c, dst_c, nullptr, nullptr, nullptr, nullptr,
        e_coarse, Wein0, b_ein,
        W01c, b1pc, Wbe2[0], b_be2,
        nullptr, nullptr, nullptr, ec, nullptr, nullptr, nullptr, flag);
    fnn2k<2, 0><<<(NC + 63) / 64, 512, 0, stream>>>(
        NC, vc, nullptr, nullptr, nullptr, ec, rp_c, cnti_c, eids_c,
        nullptr, nullptr, nullptr,
        Wbn1[0], b_bn1, Wbn2[0], b_bn2,
        nullptr, nullptr, vc, vc, nullptr, nullptr, nullptr, flag);
    // layer 1
    lin1<128, 256><<<(NC + 63) / 64, 256, 0, stream>>>(NC, vc, nullptr, Wsd_c[1],
                                                       zerob, nullptr, nullptr, Psd, zflag);
    fnn2k<1, 0><<<(EC + 63) / 64, 512, 0, stream>>>(
        EC, ec, Psd, src_c, dst_c, nullptr, nullptr, nullptr, nullptr,
        nullptr, nullptr, nullptr,
        Wbe1[1], b_be1 + 128, Wbe2[1], b_be2 + 128,
        nullptr, nullptr, ec, ec, nullptr, nullptr, nullptr, flag);
    fnn2k<2, 0><<<(NC + 63) / 64, 512, 0, stream>>>(
        NC, vc, nullptr, nullptr, nullptr, ec, rp_c, cnti_c, eids_c,
        nullptr, nullptr, nullptr,
        Wbn1[1], b_bn1 + 128, Wbn2[1], b_bn2 + 128,
        nullptr, nullptr, vc, vc, nullptr, nullptr, nullptr, flag);

    // ---- unpool (fused c_fine conditioning) ----
    fnn2k<3, 1><<<(NF + 63) / 64, 512, 0, stream>>>(
        NF, vc, nullptr, cluster, nullptr, nullptr, nullptr, nullptr, nullptr,
        c_fine, Wcond1, b_cond + 128,
        Wunp1, b_unp1, Wunp2, b_unp2,
        relb, w1last, nullptr, vf, nullptr, nullptr, nullptr, flag);

    // ---- up (fine) interaction layers; last node layer fuses out-projection ----
    // layer 0 edge: fused input projection (composite W01, reg residual)
    lin1<128, 256><<<(NF + 63) / 64, 256, 0, stream>>>(NF, vf, nullptr, Wsd_f[0],
                                                       zerob, nullptr, nullptr, Psd, zflag);
    fnn2k<1, 1><<<(EF + 63) / 64, 512, 0, stream>>>(
        EF, nullptr, Psd, src_f, dst_f, nullptr, nullptr, nullptr, nullptr,
        e_fine, Wein1, b_ein + 128,
        W01f, b1pf, Wue2[0], b_ue2,
        nullptr, nullptr, nullptr, ef, nullptr, nullptr, nullptr, flag);
    fnn2k<2, 0><<<(NF + 63) / 64, 512, 0, stream>>>(
        NF, vf, nullptr, nullptr, nullptr, ef, rp_f, cnti_f, eids_f,
        nullptr, nullptr, nullptr,
        Wun1[0], b_un1, Wun2[0], b_un2,
        nullptr, nullptr, vf, vf, nullptr, nullptr, nullptr, flag);
    // layer 1
    lin1<128, 256><<<(NF + 63) / 64, 256, 0, stream>>>(NF, vf, nullptr, Wsd_f[1],
                                                       zerob, nullptr, nullptr, Psd, zflag);
    fnn2k<1, 0><<<(EF + 63) / 64, 512, 0, stream>>>(
        EF, ef, Psd, src_f, dst_f, nullptr, nullptr, nullptr, nullptr,
        nullptr, nullptr, nullptr,
        Wue1[1], b_ue1 + 128, Wue2[1], b_ue2 + 128,
        nullptr, nullptr, ef, ef, nullptr, nullptr, nullptr, flag);
    fnn2k<2, 0><<<(NF + 63) / 64, 512, 0, stream>>>(
        NF, vf, nullptr, nullptr, nullptr, ef, rp_f, cnti_f, eids_f,
        nullptr, nullptr, nullptr,
        Wun1[1], b_un1 + 128, Wun2[1], b_un2 + 128,
        nullptr, nullptr, vf, nullptr,
        foutw, b_out, d_out, flag);
}

// Round 15
// 728.225 us; speedup vs baseline: 1.1439x; 1.1439x over previous
//
#include <hip/hip_runtime.h>
#include <hip/hip_bf16.h>

typedef __bf16 bf16_t;
typedef __bf16 bf16x8 __attribute__((ext_vector_type(8)));
typedef float f32x4 __attribute__((ext_vector_type(4)));

#define SELU_SCALE 1.0507009873554805f
#define SELU_ALPHA 1.6732632423543772f

__device__ __forceinline__ float selu_f(float x) {
    return x > 0.0f ? SELU_SCALE * x : SELU_SCALE * SELU_ALPHA * (__expf(x) - 1.0f);
}

// load 8 elements at elem_off from p (bf16 or f32 per isf) as 8 bf16 (int4)
__device__ __forceinline__ int4 load8(const void* p, size_t elem_off, int isf) {
    if (!isf) return *(const int4*)((const bf16_t*)p + elem_off);
    const float* f = (const float*)p + elem_off;
    float4 a = ((const float4*)f)[0], b = ((const float4*)f)[1];
    union { int4 i; bf16_t h[8]; } u;
    u.h[0] = (bf16_t)a.x; u.h[1] = (bf16_t)a.y; u.h[2] = (bf16_t)a.z; u.h[3] = (bf16_t)a.w;
    u.h[4] = (bf16_t)b.x; u.h[5] = (bf16_t)b.y; u.h[6] = (bf16_t)b.z; u.h[7] = (bf16_t)b.w;
    return u.i;
}

// ---------------- dtype detect: bf16 vs f32 device buffers ----------------
__global__ void detect_dtype(const unsigned short* p, int* flag) {
    if (threadIdx.x == 0) {
        float m = 0.0f;
        for (int i = 0; i < 128; i++) {
            unsigned int u = ((unsigned int)p[i]) << 16;
            float v = __uint_as_float(u);
            v = fabsf(v);
            if (!(v <= 1e3f)) { m = 1e30f; break; }
            m = fmaxf(m, v);
        }
        *flag = (m > 1e3f) ? 1 : 0;  // 1 = inputs are float32
    }
}

// ---------------- batched vector convert ----------------
struct VDesc { const void* s; bf16_t* d; int eoff; int n; };
struct VArgs { VDesc v[19]; };
__global__ void convert_vecs(VArgs a, const int* __restrict__ flag) {
    int isf = *flag;
    VDesc vd = a.v[blockIdx.y];
    int i = blockIdx.x * 256 + threadIdx.x;
    if (i < vd.n) {
        size_t idx = (size_t)vd.eoff + i;
        vd.d[i] = isf ? (bf16_t)(((const float*)vd.s)[idx]) : ((const bf16_t*)vd.s)[idx];
    }
}

// ---------------- batched weight transpose ----------------
struct TDesc { const void* s; bf16_t* d; int eoff; int Ksrc; int Ktot; int koff; };
struct TArgs { TDesc t[31]; };
__global__ void transpose_all(TArgs a, const int* __restrict__ flag) {
    int isf = *flag;
    TDesc td = a.t[blockIdx.y];
    int i = blockIdx.x * 256 + threadIdx.x;
    if (i < 128 * td.Ksrc) {
        int n = i / td.Ksrc;
        int k = i - n * td.Ksrc;
        size_t si = (size_t)td.eoff + (size_t)k * 128 + n;
        bf16_t v = isf ? (bf16_t)(((const float*)td.s)[si]) : ((const bf16_t*)td.s)[si];
        td.d[(size_t)n * td.Ktot + td.koff + k] = v;
    }
}

// ---------------- CSR build (scan-free, both graphs per launch via gridDim.y) --------
__global__ void count_dst2(const int* __restrict__ d0, int* __restrict__ c0, int E0,
                           const int* __restrict__ d1, int* __restrict__ c1, int E1) {
    const int* dst = blockIdx.y ? d1 : d0;
    int* cnt = blockIdx.y ? c1 : c0;
    int E = blockIdx.y ? E1 : E0;
    int e = blockIdx.x * 256 + threadIdx.x;
    if (e < E) atomicAdd(&cnt[dst[e]], 1);
}

// rp[i] = cur[i] = fetch-add(total, cnt[i]); disjoint segments tiling [0,E)
__global__ void seg_alloc2(const int* __restrict__ c0, int* __restrict__ rp0, int* __restrict__ cu0, int n0,
                           const int* __restrict__ c1, int* __restrict__ rp1, int* __restrict__ cu1, int n1,
                           int* __restrict__ totals) {
    const int* cnt = blockIdx.y ? c1 : c0;
    int* rp = blockIdx.y ? rp1 : rp0;
    int* cu = blockIdx.y ? cu1 : cu0;
    int n = blockIdx.y ? n1 : n0;
    int* total = totals + blockIdx.y;
    int i = blockIdx.x * 256 + threadIdx.x;
    if (i < n) { int s = atomicAdd(total, cnt[i]); rp[i] = s; cu[i] = s; }
}

__global__ void csr_scatter2(const int* __restrict__ d0, int* __restrict__ cu0, int* __restrict__ e0, int E0,
                             const int* __restrict__ d1, int* __restrict__ cu1, int* __restrict__ e1, int E1) {
    const int* dst = blockIdx.y ? d1 : d0;
    int* cur = blockIdx.y ? cu1 : cu0;
    int* eids = blockIdx.y ? e1 : e0;
    int E = blockIdx.y ? E1 : E0;
    int e = blockIdx.x * 256 + threadIdx.x;
    if (e < E) {
        unsigned s = (unsigned)atomicAdd(&cur[dst[e]], 1);
        if (s < (unsigned)E) eids[s] = e;   // bounds guard: never corrupt neighbors
    }
}

// src_p[s] = src[eids[s]], dst_p[s] = dst[eids[s]]  (edge endpoints in slot order)
__global__ void permute_ends2(const int* __restrict__ e0, const int* __restrict__ s0,
                              const int* __restrict__ d0, int* __restrict__ sp0,
                              int* __restrict__ dp0, int E0,
                              const int* __restrict__ e1, const int* __restrict__ s1,
                              const int* __restrict__ d1, int* __restrict__ sp1,
                              int* __restrict__ dp1, int E1) {
    const int* eids = blockIdx.y ? e1 : e0;
    const int* src = blockIdx.y ? s1 : s0;
    const int* dst = blockIdx.y ? d1 : d0;
    int* sp = blockIdx.y ? sp1 : sp0;
    int* dp = blockIdx.y ? dp1 : dp0;
    int E = blockIdx.y ? E1 : E0;
    int s = blockIdx.x * 256 + threadIdx.x;
    if (s < E) { int e = eids[s]; sp[s] = src[e]; dp[s] = dst[e]; }
}

// ---------------- single linear layer (external f32-or-bf16 inputs) ----------------
// out[M][N] = concat(A0[,A1])[gi?][M][K] @ Wt^T + b1 (+ b2) (+ res)
template<int K, int N>
__global__ __launch_bounds__(256) void lin1(
    int M, const void* __restrict__ A0, const void* __restrict__ A1,
    const int* __restrict__ gi,
    const bf16_t* __restrict__ Wt, const bf16_t* __restrict__ b1,
    const bf16_t* __restrict__ b2, const bf16_t* __restrict__ res,
    bf16_t* __restrict__ out, const int* __restrict__ flag)
{
    constexpr int SA = K + 8;
    constexpr int NCT = N / 64;          // 16-col tiles per wave (4 waves)
    __shared__ bf16_t sA[64 * SA];
    const int isf = *flag;
    const int tid = threadIdx.x;
    const int row0 = blockIdx.x * 64;
    const int lane16 = tid & 15;
    const int rgrp = tid >> 4;

    #pragma unroll
    for (int chunk = 0; chunk < K; chunk += 128) {
        const void* sp = chunk ? A1 : A0;
        for (int r = rgrp; r < 64; r += 16) {
            int rr = row0 + r; if (rr >= M) rr = M - 1;
            if (gi) rr = gi[rr];
            int4 u = load8(sp, (size_t)rr * 128 + lane16 * 8, isf);
            *(int4*)&sA[r * SA + chunk + lane16 * 8] = u;
        }
    }
    __syncthreads();

    const int lane = tid & 63, wave = tid >> 6;
    const int l15 = lane & 15, lk = lane >> 4;
    const int colbase = wave * (N / 4);
    f32x4 acc[4][NCT];
    const f32x4 zero = {0.f, 0.f, 0.f, 0.f};
    for (int rt = 0; rt < 4; rt++)
        for (int ct = 0; ct < NCT; ct++) acc[rt][ct] = zero;

    #pragma unroll
    for (int k0 = 0; k0 < K; k0 += 32) {
        bf16x8 wv[NCT];
        #pragma unroll
        for (int ct = 0; ct < NCT; ct++)
            wv[ct] = *(const bf16x8*)(Wt + (size_t)(colbase + ct * 16 + l15) * K + k0 + lk * 8);
        #pragma unroll
        for (int rt = 0; rt < 4; rt++) {
            bf16x8 av = *(const bf16x8*)(&sA[(rt * 16 + l15) * SA + k0 + lk * 8]);
            #pragma unroll
            for (int ct = 0; ct < NCT; ct++)
                acc[rt][ct] = __builtin_amdgcn_mfma_f32_16x16x32_bf16(av, wv[ct], acc[rt][ct], 0, 0, 0);
        }
    }

    #pragma unroll
    for (int rt = 0; rt < 4; rt++)
        #pragma unroll
        for (int ct = 0; ct < NCT; ct++) {
            int col = colbase + ct * 16 + l15;
            float bc = (float)b1[col] + (b2 ? (float)b2[col] : 0.0f);
            #pragma unroll
            for (int r = 0; r < 4; r++) {
                int grow = row0 + rt * 16 + lk * 4 + r;
                if (grow < M) {
                    float x = acc[rt][ct][r] + bc;
                    if (res) x += (float)res[(size_t)grow * N + col];
                    out[(size_t)grow * N + col] = (bf16_t)x;
                }
            }
        }
}

// ---------------- fused 2-layer FNN: 8 waves / 512 threads, 64-row tile ----------
// MODE 1 (edge): plane0 = E rows; plane1 = S = Psd[g0].lo + Psd[g1].hi.
//   INPROJ=1: plane0 staged from RAW external edge input (gie-gathered, f32-aware);
//   GEMM0 (W0t,b0) computes E0 in-place into plane0; residual = plane0 (E0).
// MODE 2 (node): plane0 = V rows; plane1 = mean of CONTIGUOUS Emat rows. K=256.
// MODE 3 (unpool): plane0 = A0[g0]; rank-1 rel*w1last on layer-1 preact.
//   INPROJ=1: plane1 staged from RAW c_fine; GEMM0 keeps conditioning cC in regs;
//   ep2 adds cC (no res pointer). sH aliases the LAST plane.
template<int MODE, int INPROJ>
__global__ __launch_bounds__(512, 8) void fnn2k(
    int M,
    const bf16_t* __restrict__ A0, const bf16_t* __restrict__ Psd,
    const int* __restrict__ g0, const int* __restrict__ g1,
    const bf16_t* __restrict__ Emat, const int* __restrict__ rp,
    const int* __restrict__ degc,
    const void* __restrict__ Araw, const int* __restrict__ gie,
    const bf16_t* __restrict__ W0t, const bf16_t* __restrict__ b0,
    const bf16_t* __restrict__ W1t, const bf16_t* __restrict__ b1,
    const bf16_t* __restrict__ W2t, const bf16_t* __restrict__ b2,
    const bf16_t* __restrict__ relb, const bf16_t* __restrict__ w1last,
    const bf16_t* __restrict__ res, bf16_t* __restrict__ out,
    const bf16_t* __restrict__ finw, const bf16_t* __restrict__ finb,
    void* __restrict__ fout, const int* __restrict__ flag)
{
    constexpr int NP = (MODE == 3 && !INPROJ) ? 1 : 2;
    constexpr int K1 = (MODE == 2) ? 256 : 128;
    constexpr int PL = 64 * 136;
    __shared__ bf16_t sA[NP * PL];
    bf16_t* sH = sA + (NP - 1) * PL;

    const int isf = *flag;
    const int tid = threadIdx.x;
    const int lane16 = tid & 15;
    const int rgrp = tid >> 4;                    // 0..31 (16-lane row groups)
    const int lane = tid & 63, wave = tid >> 6;   // 8 waves
    const int l15 = lane & 15, lk = lane >> 4;
    const int colbase = wave * 16;
    const int row0 = blockIdx.x * 64;
    const bool res_lds = (res == A0);
    const f32x4 zero = {0.f, 0.f, 0.f, 0.f};

    // ---- stage planes: each 16-lane group loads rows rgrp, rgrp+32 ----
    #pragma unroll
    for (int c = 0; c < NP; c++) {
        #pragma unroll
        for (int i = 0; i < 2; i++) {
            int r = rgrp + i * 32;
            int rr = row0 + r; if (rr >= M) rr = M - 1;
            int4 u;
            if (MODE == 1 && INPROJ && c == 0) {
                int rr2 = gie[rr];
                u = load8(Araw, (size_t)rr2 * 128 + lane16 * 8, isf);
            } else if (MODE == 1 && c == 1) {
                bf16x8 pa = *(const bf16x8*)(Psd + (size_t)g0[rr] * 256 + lane16 * 8);
                bf16x8 pb = *(const bf16x8*)(Psd + (size_t)g1[rr] * 256 + 128 + lane16 * 8);
                union { int4 i4; bf16_t h[8]; } w;
                #pragma unroll
                for (int j = 0; j < 8; j++) w.h[j] = (bf16_t)((float)pa[j] + (float)pb[j]);
                u = w.i4;
            } else if (MODE == 2 && c == 1) {
                int beg = rp[rr], deg = degc[rr];
                float a8[8] = {0.f, 0.f, 0.f, 0.f, 0.f, 0.f, 0.f, 0.f};
                const bf16_t* ep = Emat + (size_t)beg * 128 + lane16 * 8;
                for (int e = 0; e < deg; e++) {
                    bf16x8 ev = *(const bf16x8*)ep;
                    ep += 128;
                    #pragma unroll
                    for (int j = 0; j < 8; j++) a8[j] += (float)ev[j];
                }
                float inv = 1.0f / (float)(deg > 0 ? deg : 1);
                union { int4 i4; bf16_t h[8]; } w;
                #pragma unroll
                for (int j = 0; j < 8; j++) w.h[j] = (bf16_t)(a8[j] * inv);
                u = w.i4;
            } else if (MODE == 3 && c == 1) {
                // INPROJ: raw c_fine row (direct index)
                u = load8(Araw, (size_t)rr * 128 + lane16 * 8, isf);
            } else {
                const bf16_t* sp = (MODE == 3) ? A0 + (size_t)g0[rr] * 128
                                               : A0 + (size_t)rr * 128;
                u = *(const int4*)(sp + lane16 * 8);
            }
            *(int4*)&sA[c * PL + r * 136 + lane16 * 8] = u;
        }
    }
    __syncthreads();

    // ---- INPROJ front-GEMM (W0t): MODE1 -> E0 into plane0; MODE3 -> cC in regs ----
    f32x4 cC[4] = {zero, zero, zero, zero};
    if constexpr (INPROJ) {
        constexpr int PX = (MODE == 1) ? 0 : 1;
        f32x4 a0r[4];
        #pragma unroll
        for (int rt = 0; rt < 4; rt++) a0r[rt] = zero;
        #pragma unroll
        for (int k0 = 0; k0 < 128; k0 += 32) {
            bf16x8 w0 = *(const bf16x8*)(W0t + (size_t)(colbase + l15) * 128 + k0 + lk * 8);
            #pragma unroll
            for (int rt = 0; rt < 4; rt++) {
                bf16x8 av = *(const bf16x8*)(&sA[PX * PL + (rt * 16 + l15) * 136 + k0 + lk * 8]);
                a0r[rt] = __builtin_amdgcn_mfma_f32_16x16x32_bf16(av, w0, a0r[rt], 0, 0, 0);
            }
        }
        __syncthreads();   // all GEMM0 reads of the raw plane complete
        int col = colbase + l15;
        float b0c = (float)b0[col];
        if constexpr (MODE == 1) {
            #pragma unroll
            for (int rt = 0; rt < 4; rt++)
                #pragma unroll
                for (int r = 0; r < 4; r++) {
                    int lrow = rt * 16 + lk * 4 + r;
                    sA[lrow * 136 + col] = (bf16_t)(a0r[rt][r] + b0c);
                }
            __syncthreads();   // E0 visible to all waves for GEMM1
        } else {
            #pragma unroll
            for (int rt = 0; rt < 4; rt++)
                #pragma unroll
                for (int r = 0; r < 4; r++) cC[rt][r] = a0r[rt][r] + b0c;
        }
    }

    // ---- GEMM1: wave computes cols [colbase, colbase+16), rows 0..63 ----
    f32x4 acc[4];
    #pragma unroll
    for (int rt = 0; rt < 4; rt++) acc[rt] = zero;
    #pragma unroll
    for (int k0 = 0; k0 < K1; k0 += 32) {
        bf16x8 w0 = *(const bf16x8*)(W1t + (size_t)(colbase + l15) * K1 + k0 + lk * 8);
        #pragma unroll
        for (int rt = 0; rt < 4; rt++) {
            bf16x8 av = *(const bf16x8*)(&sA[(k0 / 128) * PL + (rt * 16 + l15) * 136 + (k0 & 127) + lk * 8]);
            acc[rt] = __builtin_amdgcn_mfma_f32_16x16x32_bf16(av, w0, acc[rt], 0, 0, 0);
        }
    }
    // MODE 1: GEMM1 never reads plane1, and ep1 updates plane1 in place at
    // thread-private addresses -> no barrier needed. MODE 2/3 overwrite a plane
    // other waves may still be reading.
    if (MODE != 1) __syncthreads();

    // ---- epilogue 1: bias (+S / +rank-1) + SELU -> sH ----
    {
        int col = colbase + l15;
        float b1c = (float)b1[col];
        float wlc = (MODE == 3) ? (float)w1last[col] : 0.0f;
        #pragma unroll
        for (int rt = 0; rt < 4; rt++)
            #pragma unroll
            for (int r = 0; r < 4; r++) {
                int lrow = rt * 16 + lk * 4 + r;
                int grow = row0 + lrow;
                float x = acc[rt][r] + b1c;
                if (MODE == 1) x += (float)sH[lrow * 136 + col];   // S plane, in place
                if (MODE == 3) {
                    float rv = (grow < M) ? (float)relb[grow] : 0.0f;
                    x += rv * wlc;
                }
                x = selu_f(x);
                sH[lrow * 136 + col] = (bf16_t)x;
            }
    }
    __syncthreads();

    // ---- GEMM2 (K2 = 128 from sH) ----
    f32x4 acc2[4];
    #pragma unroll
    for (int rt = 0; rt < 4; rt++) acc2[rt] = zero;
    #pragma unroll
    for (int k0 = 0; k0 < 128; k0 += 32) {
        bf16x8 w0 = *(const bf16x8*)(W2t + (size_t)(colbase + l15) * 128 + k0 + lk * 8);
        #pragma unroll
        for (int rt = 0; rt < 4; rt++) {
            bf16x8 av = *(const bf16x8*)(&sH[(rt * 16 + l15) * 136 + k0 + lk * 8]);
            acc2[rt] = __builtin_amdgcn_mfma_f32_16x16x32_bf16(av, w0, acc2[rt], 0, 0, 0);
        }
    }
    if (finw) __syncthreads();  // about to rewrite sH with final values

    // ---- epilogue 2: bias + residual -> out (+ stash for fused out-proj) ----
    {
        int col = colbase + l15;
        float b2c = (float)b2[col];
        #pragma unroll
        for (int rt = 0; rt < 4; rt++)
            #pragma unroll
            for (int r = 0; r < 4; r++) {
                int lrow = rt * 16 + lk * 4 + r;
                int grow = row0 + lrow;
                if (grow < M) {
                    float x = acc2[rt][r] + b2c;
                    if constexpr (MODE == 3 && INPROJ) {
                        x += cC[rt][r];                                  // conditioning
                    }
                    if constexpr (MODE == 1 && INPROJ) {
                        x += (float)sA[lrow * 136 + col];                // residual = E0
                    } else {
                        if (res) {
                            float rv = (res_lds && NP > 1) ? (float)sA[lrow * 136 + col]
                                                           : (float)res[(size_t)grow * 128 + col];
                            x += rv;
                        }
                    }
                    bf16_t xb = (bf16_t)x;
                    if (out) out[(size_t)grow * 128 + col] = xb;
                    if (finw) sH[lrow * 136 + col] = xb;
                }
            }
    }

    // ---- fused final projection 128 -> 4 ----
    if (finw) {
        __syncthreads();
        if (tid < 256) {
            int orow = tid >> 2, c = tid & 3;
            int grow = row0 + orow;
            if (grow < M) {
                float s = (float)finb[c];
                #pragma unroll
                for (int k = 0; k < 128; k++)
                    s += (float)sH[orow * 136 + k] * (float)finw[k * 4 + c];
                if (isf) ((float*)fout)[(size_t)grow * 4 + c] = s;
                else     ((bf16_t*)fout)[(size_t)grow * 4 + c] = (bf16_t)s;
            }
        }
    }
}

extern "C" void kernel_launch(void* const* d_in, const int* in_sizes, int n_in,
                              void* d_out, int out_size, void* d_ws, size_t ws_size,
                              hipStream_t stream) {
    const int NC = 25000, NF = 100000, EC = 100000, EF = 400000;

    const void* v_in      = d_in[0];
    const void* c_coarse  = d_in[1];
    const void* c_fine    = d_in[2];
    const void* e_coarse  = d_in[3];
    const void* e_fine    = d_in[4];
    const void* rel_dist  = d_in[5];
    const int*  ei_c      = (const int*)d_in[6];
    const int*  ei_f      = (const int*)d_in[7];
    const int*  cluster   = (const int*)d_in[8];
    const void* in_node_w = d_in[9];
    const void* in_node_b = d_in[10];
    const void* cond_w    = d_in[11];
    const void* cond_b    = d_in[12];
    const void* edge_in_w = d_in[13];
    const void* edge_in_b = d_in[14];
    const void* bn_ew1    = d_in[15];
    const void* bn_eb1    = d_in[16];
    const void* bn_ew2    = d_in[17];
    const void* bn_eb2    = d_in[18];
    const void* bn_nw1    = d_in[19];
    const void* bn_nb1    = d_in[20];
    const void* bn_nw2    = d_in[21];
    const void* bn_nb2    = d_in[22];
    const void* unp_w1    = d_in[23];
    const void* unp_b1    = d_in[24];
    const void* unp_w2    = d_in[25];
    const void* unp_b2    = d_in[26];
    const void* up_ew1    = d_in[27];
    const void* up_eb1    = d_in[28];
    const void* up_ew2    = d_in[29];
    const void* up_eb2    = d_in[30];
    const void* up_nw1    = d_in[31];
    const void* up_nb1    = d_in[32];
    const void* up_nw2    = d_in[33];
    const void* up_nb2    = d_in[34];
    const void* out_w     = d_in[35];
    const void* out_b     = d_in[36];

    const int* src_c = ei_c, * dst_c = ei_c + EC;
    const int* src_f = ei_f, * dst_f = ei_f + EF;

    // ---- workspace carve ----
    char* base = (char*)d_ws;
    size_t off = 0;
    auto carve = [&](size_t bytes) -> void* {
        void* p = base + off;
        off += (bytes + 255) & ~(size_t)255;
        return p;
    };
    int*    flag   = (int*)carve(256);
    int*    zflag  = (int*)carve(256);          // always 0: force-bf16 path for lin1
    int*    totals = (int*)carve(256);
    bf16_t* vc     = (bf16_t*)carve((size_t)NC * 128 * 2);
    bf16_t* vf     = (bf16_t*)carve((size_t)NF * 128 * 2);
    bf16_t* ef     = (bf16_t*)carve((size_t)EF * 128 * 2);   // ec aliases the front
    bf16_t* ec     = ef;
    bf16_t* Psd    = (bf16_t*)carve((size_t)NF * 256 * 2);   // [node][Ps|Pd], reused c/f
    int*    cnti_c = (int*)carve((size_t)NC * 4);
    int*    cnti_f = (int*)carve((size_t)NF * 4);
    int*    rp_c   = (int*)carve((size_t)NC * 4);
    int*    rp_f   = (int*)carve((size_t)NF * 4);
    int*    cur_c  = (int*)carve((size_t)NC * 4);
    int*    cur_f  = (int*)carve((size_t)NF * 4);
    int*    srcp_c = (int*)carve((size_t)EC * 4);
    int*    dstp_c = (int*)carve((size_t)EC * 4);
    int*    srcp_f = (int*)carve((size_t)EF * 4);
    int*    dstp_f = (int*)carve((size_t)EF * 4);

    auto cw = [&](size_t elems) -> bf16_t* { return (bf16_t*)carve(elems * 2); };
    bf16_t* Wic    = cw(128 * 256);
    bf16_t* Wein0  = cw(128 * 128);
    bf16_t* Wein1  = cw(128 * 128);
    bf16_t* Wcond1 = cw(128 * 128);
    bf16_t* Wbe1[2] = { cw(128 * 128), cw(128 * 128) };       // We^T only (K=128)
    bf16_t* Wsd_c[2] = { cw(256 * 128), cw(256 * 128) };      // [Ws^T ; Wd^T]
    bf16_t* Wbe2[2] = { cw(128 * 128), cw(128 * 128) };
    bf16_t* Wbn1[2] = { cw(128 * 256), cw(128 * 256) };
    bf16_t* Wbn2[2] = { cw(128 * 128), cw(128 * 128) };
    bf16_t* Wunp1 = cw(128 * 128);
    bf16_t* Wunp2 = cw(128 * 128);
    bf16_t* Wue1[2] = { cw(128 * 128), cw(128 * 128) };
    bf16_t* Wsd_f[2] = { cw(256 * 128), cw(256 * 128) };
    bf16_t* Wue2[2] = { cw(128 * 128), cw(128 * 128) };
    bf16_t* Wun1[2] = { cw(128 * 256), cw(128 * 256) };
    bf16_t* Wun2[2] = { cw(128 * 128), cw(128 * 128) };
    bf16_t* b_in   = cw(128);
    bf16_t* b_cond = cw(256);
    bf16_t* b_ein  = cw(256);
    bf16_t* b_be1  = cw(256);
    bf16_t* b_be2  = cw(256);
    bf16_t* b_bn1  = cw(256);
    bf16_t* b_bn2  = cw(256);
    bf16_t* b_unp1 = cw(128);
    bf16_t* b_unp2 = cw(128);
    bf16_t* b_ue1  = cw(256);
    bf16_t* b_ue2  = cw(256);
    bf16_t* b_un1  = cw(256);
    bf16_t* b_un2  = cw(256);
    bf16_t* b_out  = cw(8);
    bf16_t* w1last = cw(128);
    bf16_t* relb   = cw(NF);
    bf16_t* foutw  = cw(512);
    bf16_t* zerob  = cw(256);                    // zero bias for Psd passes
    // eids at the END of the carve: even a buggy OOB scatter can't corrupt weights
    int*    eids_c = (int*)carve((size_t)EC * 4);
    int*    eids_f = (int*)carve((size_t)EF * 4);

    // ---- dtype detection + zero-init ----
    detect_dtype<<<1, 64, 0, stream>>>((const unsigned short*)in_node_b, flag);
    hipMemsetAsync(zflag, 0, 256, stream);
    hipMemsetAsync(zerob, 0, 512, stream);

    // ---- vector converts ----
    VArgs va; int vi = 0;
    auto addV = [&](const void* s, bf16_t* d, int eoff, int n) {
        va.v[vi].s = s; va.v[vi].d = d; va.v[vi].eoff = eoff; va.v[vi].n = n; vi++;
    };
    addV(in_node_b, b_in, 0, 128);
    addV(cond_b, b_cond, 0, 256);
    addV(edge_in_b, b_ein, 0, 256);
    addV(bn_eb1, b_be1, 0, 256);  addV(bn_eb2, b_be2, 0, 256);
    addV(bn_nb1, b_bn1, 0, 256);  addV(bn_nb2, b_bn2, 0, 256);
    addV(unp_b1, b_unp1, 0, 128); addV(unp_b2, b_unp2, 0, 128);
    addV(up_eb1, b_ue1, 0, 256);  addV(up_eb2, b_ue2, 0, 256);
    addV(up_nb1, b_un1, 0, 256);  addV(up_nb2, b_un2, 0, 256);
    addV(out_b, b_out, 0, 4);
    addV(unp_w1, w1last, 128 * 128, 128);
    addV(rel_dist, relb, 0, NF);
    addV(out_w, foutw, 0, 512);
    dim3 vg((NF + 255) / 256, vi);
    convert_vecs<<<vg, 256, 0, stream>>>(va, flag);

    // ---- weight transposes ----
    TArgs ta; int ti = 0;
    auto addT = [&](const void* s, bf16_t* d, int eoff, int Ksrc, int Ktot, int koff) {
        ta.t[ti].s = s; ta.t[ti].d = d; ta.t[ti].eoff = eoff;
        ta.t[ti].Ksrc = Ksrc; ta.t[ti].Ktot = Ktot; ta.t[ti].koff = koff; ti++;
    };
    addT(in_node_w, Wic, 0, 128, 256, 0);
    addT(cond_w,    Wic, 0, 128, 256, 128);
    addT(edge_in_w, Wein0, 0, 128, 128, 0);
    addT(edge_in_w, Wein1, 16384, 128, 128, 0);
    addT(cond_w,    Wcond1, 16384, 128, 128, 0);
    for (int i = 0; i < 2; i++) {
        // edge W1 split: rows [0,128)=We, [128,256)=Ws, [256,384)=Wd
        addT(bn_ew1, Wbe1[i],           i * 49152,         128, 128, 0);
        addT(bn_ew1, Wsd_c[i],          i * 49152 + 16384, 128, 128, 0);
        addT(bn_ew1, Wsd_c[i] + 16384,  i * 49152 + 32768, 128, 128, 0);
        addT(bn_ew2, Wbe2[i], i * 16384, 128, 128, 0);
        addT(bn_nw1, Wbn1[i], i * 32768, 256, 256, 0);
        addT(bn_nw2, Wbn2[i], i * 16384, 128, 128, 0);
        addT(up_ew1, Wue1[i],           i * 49152,         128, 128, 0);
        addT(up_ew1, Wsd_f[i],          i * 49152 + 16384, 128, 128, 0);
        addT(up_ew1, Wsd_f[i] + 16384,  i * 49152 + 32768, 128, 128, 0);
        addT(up_ew2, Wue2[i], i * 16384, 128, 128, 0);
        addT(up_nw1, Wun1[i], i * 32768, 256, 256, 0);
        addT(up_nw2, Wun2[i], i * 16384, 128, 128, 0);
    }
    addT(unp_w1, Wunp1, 0, 128, 128, 0);
    addT(unp_w2, Wunp2, 0, 128, 128, 0);
    dim3 tg((128 * 256 + 255) / 256, ti);
    transpose_all<<<tg, 256, 0, stream>>>(ta, flag);

    // ---- CSR build (counts -> scan-free segment alloc -> scatter -> endpoint perm) ----
    hipMemsetAsync(cnti_c, 0, (size_t)NC * 4, stream);
    hipMemsetAsync(cnti_f, 0, (size_t)NF * 4, stream);
    hipMemsetAsync(totals, 0, 256, stream);
    dim3 ge((EF + 255) / 256, 2), gn((NF + 255) / 256, 2);
    count_dst2<<<ge, 256, 0, stream>>>(dst_c, cnti_c, EC, dst_f, cnti_f, EF);
    seg_alloc2<<<gn, 256, 0, stream>>>(cnti_c, rp_c, cur_c, NC, cnti_f, rp_f, cur_f, NF, totals);
    csr_scatter2<<<ge, 256, 0, stream>>>(dst_c, cur_c, eids_c, EC, dst_f, cur_f, eids_f, EF);
    permute_ends2<<<ge, 256, 0, stream>>>(eids_c, src_c, dst_c, srcp_c, dstp_c, EC,
                                          eids_f, src_f, dst_f, srcp_f, dstp_f, EF);

    // ---- input projection + coarse conditioning (fused K=256) ----
    lin1<256, 128><<<(NC + 63) / 64, 256, 0, stream>>>(NC, v_in, c_coarse, nullptr, Wic,
                                                       b_in, b_cond, nullptr, vc, flag);

    // ---- bottleneck (coarse) interaction layers ----
    // layer 0 edge: fused input projection from raw e_coarse (slot-gathered)
    lin1<128, 256><<<(NC + 63) / 64, 256, 0, stream>>>(NC, vc, nullptr, nullptr, Wsd_c[0],
                                                       zerob, nullptr, nullptr, Psd, zflag);
    fnn2k<1, 1><<<(EC + 63) / 64, 512, 0, stream>>>(
        EC, nullptr, Psd, srcp_c, dstp_c, nullptr, nullptr, nullptr,
        e_coarse, eids_c, Wein0, b_ein,
        Wbe1[0], b_be1, Wbe2[0], b_be2,
        nullptr, nullptr, nullptr, ec, nullptr, nullptr, nullptr, flag);
    fnn2k<2, 0><<<(NC + 63) / 64, 512, 0, stream>>>(
        NC, vc, nullptr, nullptr, nullptr, ec, rp_c, cnti_c,
        nullptr, nullptr, nullptr, nullptr,
        Wbn1[0], b_bn1, Wbn2[0], b_bn2,
        nullptr, nullptr, vc, vc, nullptr, nullptr, nullptr, flag);
    // layer 1
    lin1<128, 256><<<(NC + 63) / 64, 256, 0, stream>>>(NC, vc, nullptr, nullptr, Wsd_c[1],
                                                       zerob, nullptr, nullptr, Psd, zflag);
    fnn2k<1, 0><<<(EC + 63) / 64, 512, 0, stream>>>(
        EC, ec, Psd, srcp_c, dstp_c, nullptr, nullptr, nullptr,
        nullptr, nullptr, nullptr, nullptr,
        Wbe1[1], b_be1 + 128, Wbe2[1], b_be2 + 128,
        nullptr, nullptr, ec, ec, nullptr, nullptr, nullptr, flag);
    fnn2k<2, 0><<<(NC + 63) / 64, 512, 0, stream>>>(
        NC, vc, nullptr, nullptr, nullptr, ec, rp_c, cnti_c,
        nullptr, nullptr, nullptr, nullptr,
        Wbn1[1], b_bn1 + 128, Wbn2[1], b_bn2 + 128,
        nullptr, nullptr, vc, vc, nullptr, nullptr, nullptr, flag);

    // ---- unpool (fused c_fine conditioning) ----
    fnn2k<3, 1><<<(NF + 63) / 64, 512, 0, stream>>>(
        NF, vc, nullptr, cluster, nullptr, nullptr, nullptr, nullptr,
        c_fine, nullptr, Wcond1, b_cond + 128,
        Wunp1, b_unp1, Wunp2, b_unp2,
        relb, w1last, nullptr, vf, nullptr, nullptr, nullptr, flag);

    // ---- up (fine) interaction layers; last node layer fuses out-projection ----
    // layer 0 edge: fused input projection from raw e_fine (slot-gathered)
    lin1<128, 256><<<(NF + 63) / 64, 256, 0, stream>>>(NF, vf, nullptr, nullptr, Wsd_f[0],
                                                       zerob, nullptr, nullptr, Psd, zflag);
    fnn2k<1, 1><<<(EF + 63) / 64, 512, 0, stream>>>(
        EF, nullptr, Psd, srcp_f, dstp_f, nullptr, nullptr, nullptr,
        e_fine, eids_f, Wein1, b_ein + 128,
        Wue1[0], b_ue1, Wue2[0], b_ue2,
        nullptr, nullptr, nullptr, ef, nullptr, nullptr, nullptr, flag);
    fnn2k<2, 0><<<(NF + 63) / 64, 512, 0, stream>>>(
        NF, vf, nullptr, nullptr, nullptr, ef, rp_f, cnti_f,
        nullptr, nullptr, nullptr, nullptr,
        Wun1[0], b_un1, Wun2[0], b_un2,
        nullptr, nullptr, vf, vf, nullptr, nullptr, nullptr, flag);
    // layer 1
    lin1<128, 256><<<(NF + 63) / 64, 256, 0, stream>>>(NF, vf, nullptr, nullptr, Wsd_f[1],
                                                       zerob, nullptr, nullptr, Psd, zflag);
    fnn2k<1, 0><<<(EF + 63) / 64, 512, 0, stream>>>(
        EF, ef, Psd, srcp_f, dstp_f, nullptr, nullptr, nullptr,
        nullptr, nullptr, nullptr, nullptr,
        Wue1[1], b_ue1 + 128, Wue2[1], b_ue2 + 128,
        nullptr, nullptr, ef, ef, nullptr, nullptr, nullptr, flag);
    fnn2k<2, 0><<<(NF + 63) / 64, 512, 0, stream>>>(
        NF, vf, nullptr, nullptr, nullptr, ef, rp_f, cnti_f,
        nullptr, nullptr, nullptr, nullptr,
        Wun1[1], b_un1 + 128, Wun2[1], b_un2 + 128,
        nullptr, nullptr, vf, nullptr,
        foutw, b_out, d_out, flag);
}